// Round 8
// baseline (97.520 us; speedup 1.0000x reference)
//
#include <hip/hip_runtime.h>
#include <math.h>

// Problem constants (from reference):
//   vol: (B=1, C=1, W=96, H=96, D=64) float32, row-major -> vol[(x*96+y)*64+z]
//   out: (B,C,U=96,A=90,V=64) float32 -> out[(u*90+a)*64+v]
namespace {
constexpr int NA = 90, NU = 96, NV = 64, NW = 96, NH = 96, ND = 64;
constexpr int NRAY   = NA * NU;      // 8640
constexpr int NSTEPS = NH + NW + 2;  // 194
constexpr int ROW    = 209;          // LDS row (194 padded to x16, odd stride)
constexpr int TILE   = 8;            // rays per block = waves per block
constexpr int NBLK   = NRAY / TILE;  // 1080 blocks
}

// ATTRIBUTION ROUND (R8): identical to R7 except the gather loop runs TWICE
// (pass 2 bit-identical, CSE-blocked by asm memory clobber), output is the
// exact 0.5*(A+B) = A. dur(R8)-dur(R7) isolates the gather-phase cost G that
// rocprof cannot attribute inside the fused kernel (R4/R5/R7 all ~47.5us with
// wildly different gather structures; the poison fills saturate top-5 so a
// split-kernel profile is invisible). T = 47.4 - G decides round 9's target.
__global__ __launch_bounds__(512)
void siddon_fused(const float* __restrict__ vol, float* __restrict__ out)
{
    __shared__ int   sOff[TILE * ROW];   // BYTE offset of vol row
    __shared__ float sW  [TILE * ROW];   // segment weight
    __shared__ int   sCnt[TILE];         // entry count padded to multiple of 16

    const int tid  = threadIdx.x;
    const int tile = blockIdx.x;

    // ---------------- Phase 1: trace (wave 0, lanes 0..TILE-1) ----------------
    if (tid < 64) {
        const int  rl     = tid;
        const bool tracer = rl < TILE;
        const int  ray    = tile * TILE + (tracer ? rl : 0);
        const int  a = ray / NU;
        const int  u = ray - a * NU;

        const float EPSf = 1e-12f;
        const float INF  = __builtin_inff();
        const float DIAG = 1.41421356237309514547f;

        const float ang = (float)a * (float)(3.14159265358979323846 / 90.0);
        const float dx = (float)cos((double)ang);
        const float dy = (float)sin((double)ang);
        const float uu = (float)u - 47.5f;
        const float x0 = __fmul_rn(-uu, dy);
        const float y0 = __fmul_rn( uu, dx);

        const float xmin = -47.5f, xmax = 47.5f;
        const float ymin = -47.5f, ymax = 47.5f;

        float tx0, tx1;
        {
            const bool par = fabsf(dx) < EPSf;
            const float safe = par ? 1.0f : dx;
            const float t0 = __fdiv_rn(xmin - x0, safe);
            const float t1 = __fdiv_rn(xmax - x0, safe);
            const float lo = fminf(t0, t1), hi = fmaxf(t0, t1);
            const bool inside = (x0 >= xmin) && (x0 <= xmax);
            tx0 = par ? (inside ? -INF : INF) : lo;
            tx1 = par ? (inside ?  INF : -INF) : hi;
        }
        float ty0, ty1;
        {
            const bool par = fabsf(dy) < EPSf;
            const float safe = par ? 1.0f : dy;
            const float t0 = __fdiv_rn(ymin - y0, safe);
            const float t1 = __fdiv_rn(ymax - y0, safe);
            const float lo = fminf(t0, t1), hi = fmaxf(t0, t1);
            const bool inside = (y0 >= ymin) && (y0 <= ymax);
            ty0 = par ? (inside ? -INF : INF) : lo;
            ty1 = par ? (inside ?  INF : -INF) : hi;
        }

        const float t_entry = fmaxf(tx0, ty0);
        const float t_exit  = fminf(tx1, ty1);
        bool  alive = tracer && (t_entry < t_exit);
        const float te  = (t_entry < t_exit) ? t_entry : 0.0f;
        const float tex = (t_entry < t_exit) ? t_exit  : 0.0f;

        float x = __fadd_rn(x0, __fmul_rn(te, dx));
        float y = __fadd_rn(y0, __fmul_rn(te, dy));
        int i = (int)fminf(fmaxf(rintf(__fadd_rn(x, 47.5f)), 0.0f), 95.0f);
        int j = (int)fminf(fmaxf(rintf(__fadd_rn(y, 47.5f)), 0.0f), 95.0f);
        float t = te;

        const bool okx = fabsf(dx) > EPSf;
        const bool oky = fabsf(dy) > EPSf;
        const float inv_dx = okx ? __fdiv_rn(1.0f, dx) : 0.0f;
        const float inv_dy = oky ? __fdiv_rn(1.0f, dy) : 0.0f;
        const float wscale = __fdiv_rn(DIAG, fmaxf(fabsf(dx) + fabsf(dy), EPSf));
        const float tex_m_eps = __fadd_rn(tex, -EPSf);
        const float cx = (dx > 0.0f) ? -47.0f : -48.0f;
        const float cy = (dy > 0.0f) ? -47.0f : -48.0f;
        float xn = (float)i + cx;
        float yn = (float)j + cy;
        const float sxf = (dx > 0.0f) ? 1.0f : -1.0f;
        const float syf = (dy > 0.0f) ? 1.0f : -1.0f;
        const int   si  = (dx > 0.0f) ? 1 : -1;
        const int   sj  = (dy > 0.0f) ? 1 : -1;

        int n = 0;
        for (int step = 0; step < NSTEPS; ++step) {
            const bool valid = alive && (t < tex_m_eps);
            if (!__ballot(valid)) break;
            if (valid) {
                const float txc = okx ? __fmul_rn(xn - x, inv_dx) : INF;
                const float tyc = oky ? __fmul_rn(yn - y, inv_dy) : INF;
                const float dt  = fminf(fminf(txc, tyc), __fadd_rn(tex, -t));
                const float seg = fmaxf(0.0f, __fmul_rn(dt, wscale));

                sOff[rl * ROW + n] = (i * NH + j) << 8;
                sW  [rl * ROW + n] = seg;
                ++n;

                const bool cndx = (txc <= tyc);
                const bool cndy = (tyc <= txc);
                const int i_n = i + (cndx ? si : 0);
                const int j_n = j + (cndy ? sj : 0);
                xn += cndx ? sxf : 0.0f;
                yn += cndy ? syf : 0.0f;
                const bool inb = ((unsigned)i_n < (unsigned)NW) &&
                                 ((unsigned)j_n < (unsigned)NH);
                x = __fadd_rn(x, __fmul_rn(dx, dt));
                y = __fadd_rn(y, __fmul_rn(dy, dt));
                t = __fadd_rn(t, dt);
                i = i_n; j = j_n;
                alive = inb;
            }
        }
        if (tracer) {
            const int n16 = (n + 15) & ~15;
            for (int p = n; p < n16; ++p) {
                sOff[rl * ROW + p] = 0;
                sW  [rl * ROW + p] = 0.0f;
            }
            sCnt[rl] = n16;
        }
    }
    __syncthreads();

    // ---------------- Phase 2: gather (wave w -> ray w), TWICE ----------------
    const int wid  = tid >> 6;
    const int lane = tid & 63;
    const int r    = lane >> 4;
    const int sub  = lane & 15;
    const int subOff = sub << 4;

    const int cnt = sCnt[wid];
    const int*   __restrict__ oRow = &sOff[wid * ROW + r];
    const float* __restrict__ wRow = &sW  [wid * ROW + r];
    const char*  __restrict__ vb   = (const char*)vol;

    // ---- pass A ----
    float4 aA = {0,0,0,0}, aB = {0,0,0,0}, aC = {0,0,0,0}, aD = {0,0,0,0};
    for (int n = 0; n < cnt; n += 16) {
        const int o0 = oRow[n];
        const int o1 = oRow[n + 4];
        const int o2 = oRow[n + 8];
        const int o3 = oRow[n + 12];
        const float w0 = wRow[n];
        const float w1 = wRow[n + 4];
        const float w2 = wRow[n + 8];
        const float w3 = wRow[n + 12];
        const float4 v0 = *(const float4*)(vb + (o0 + subOff));
        const float4 v1 = *(const float4*)(vb + (o1 + subOff));
        const float4 v2 = *(const float4*)(vb + (o2 + subOff));
        const float4 v3 = *(const float4*)(vb + (o3 + subOff));
        aA.x = fmaf(w0, v0.x, aA.x); aA.y = fmaf(w0, v0.y, aA.y);
        aA.z = fmaf(w0, v0.z, aA.z); aA.w = fmaf(w0, v0.w, aA.w);
        aB.x = fmaf(w1, v1.x, aB.x); aB.y = fmaf(w1, v1.y, aB.y);
        aB.z = fmaf(w1, v1.z, aB.z); aB.w = fmaf(w1, v1.w, aB.w);
        aC.x = fmaf(w2, v2.x, aC.x); aC.y = fmaf(w2, v2.y, aC.y);
        aC.z = fmaf(w2, v2.z, aC.z); aC.w = fmaf(w2, v2.w, aC.w);
        aD.x = fmaf(w3, v3.x, aD.x); aD.y = fmaf(w3, v3.y, aD.y);
        aD.z = fmaf(w3, v3.z, aD.z); aD.w = fmaf(w3, v3.w, aD.w);
    }

    // block CSE/fusion of the two passes: force memory re-reads in pass B
    asm volatile("" ::: "memory");

    // ---- pass B (bit-identical computation) ----
    float4 bA = {0,0,0,0}, bB = {0,0,0,0}, bC = {0,0,0,0}, bD = {0,0,0,0};
    for (int n = 0; n < cnt; n += 16) {
        const int o0 = oRow[n];
        const int o1 = oRow[n + 4];
        const int o2 = oRow[n + 8];
        const int o3 = oRow[n + 12];
        const float w0 = wRow[n];
        const float w1 = wRow[n + 4];
        const float w2 = wRow[n + 8];
        const float w3 = wRow[n + 12];
        const float4 v0 = *(const float4*)(vb + (o0 + subOff));
        const float4 v1 = *(const float4*)(vb + (o1 + subOff));
        const float4 v2 = *(const float4*)(vb + (o2 + subOff));
        const float4 v3 = *(const float4*)(vb + (o3 + subOff));
        bA.x = fmaf(w0, v0.x, bA.x); bA.y = fmaf(w0, v0.y, bA.y);
        bA.z = fmaf(w0, v0.z, bA.z); bA.w = fmaf(w0, v0.w, bA.w);
        bB.x = fmaf(w1, v1.x, bB.x); bB.y = fmaf(w1, v1.y, bB.y);
        bB.z = fmaf(w1, v1.z, bB.z); bB.w = fmaf(w1, v1.w, bB.w);
        bC.x = fmaf(w2, v2.x, bC.x); bC.y = fmaf(w2, v2.y, bC.y);
        bC.z = fmaf(w2, v2.z, bC.z); bC.w = fmaf(w2, v2.w, bC.w);
        bD.x = fmaf(w3, v3.x, bD.x); bD.y = fmaf(w3, v3.y, bD.y);
        bD.z = fmaf(w3, v3.z, bD.z); bD.w = fmaf(w3, v3.w, bD.w);
    }

    // exact: pass B == pass A bitwise -> (A+B)*0.5 == A
    float sxA = (aA.x + aB.x) + (aC.x + aD.x);
    float syA = (aA.y + aB.y) + (aC.y + aD.y);
    float szA = (aA.z + aB.z) + (aC.z + aD.z);
    float swA = (aA.w + aB.w) + (aC.w + aD.w);
    float sxB = (bA.x + bB.x) + (bC.x + bD.x);
    float syB = (bA.y + bB.y) + (bC.y + bD.y);
    float szB = (bA.z + bB.z) + (bC.z + bD.z);
    float swB = (bA.w + bB.w) + (bC.w + bD.w);
    float sx = 0.5f * (sxA + sxB);
    float sy = 0.5f * (syA + syB);
    float sz = 0.5f * (szA + szB);
    float sw = 0.5f * (swA + swB);

    sx += __shfl_xor(sx, 16, 64);  sy += __shfl_xor(sy, 16, 64);
    sz += __shfl_xor(sz, 16, 64);  sw += __shfl_xor(sw, 16, 64);
    sx += __shfl_xor(sx, 32, 64);  sy += __shfl_xor(sy, 32, 64);
    sz += __shfl_xor(sz, 32, 64);  sw += __shfl_xor(sw, 32, 64);

    if (lane < 16) {
        const int ray = tile * TILE + wid;
        const int a = ray / NU;
        const int u = ray - a * NU;
        float4 res; res.x = sx; res.y = sy; res.z = sz; res.w = sw;
        *(float4*)(out + (u * NA + a) * NV + (sub << 2)) = res;
    }
}

extern "C" void kernel_launch(void* const* d_in, const int* in_sizes, int n_in,
                              void* d_out, int out_size, void* d_ws, size_t ws_size,
                              hipStream_t stream) {
    const float* vol = (const float*)d_in[0];
    float* out = (float*)d_out;
    hipLaunchKernelGGL(siddon_fused, dim3(NBLK), dim3(512), 0, stream, vol, out);
}